// Round 1
// baseline (35.525 us; speedup 1.0000x reference)
//
#include <hip/hip_runtime.h>
#include <math.h>

// SubGL aggregation kernel.
// sequence    [B,L]      int32
// seq_neighbor[B,L,N]    int32
// rel_neigh   [B,L,N]    int32
// user_emb    [USER,D]   f32  (D=128)
// rel_emb     [R,R]      f32  (R=3)
// weight_b    [R,1]      f32
// out         [B,L,D]    f32
//
// out[b,l,:] = normalize(user_emb[seq[b,l]] + sum_n w[b,l,n]*user_emb[nbr[b,l,n]])
// w[b,l,n]   = dot(rel_emb[rel_neigh[b,l,n]], softmax(weight_b))

#define BB 64
#define LL 200
#define NN 32
#define DD 128
#define RR 3

// 32 lanes per (b,l) pair; each lane owns one float4 chunk (4 dims of 128).
// 256-thread block = 8 pairs. Grid = B*L/8 = 1600 blocks.
__global__ __launch_bounds__(256) void subgl_kernel(
    const int* __restrict__ sequence,
    const int* __restrict__ seq_neighbor,
    const int* __restrict__ rel_neigh,
    const float* __restrict__ user_emb,
    const float* __restrict__ rel_emb,
    const float* __restrict__ weight_b,
    float* __restrict__ out)
{
    const int tid   = threadIdx.x;
    const int chunk = tid & 31;          // float4 chunk within the row, also "owned neighbor"
    const int pair  = tid >> 5;          // 0..7 within block
    const int bl    = blockIdx.x * 8 + pair;   // (b*L + l), exact: 1600*8 = 12800

    // beta = softmax(weight_b) -- 3 scalars, recomputed per thread (trivial)
    const float wb0 = weight_b[0], wb1 = weight_b[1], wb2 = weight_b[2];
    const float mx  = fmaxf(fmaxf(wb0, wb1), wb2);
    const float e0 = expf(wb0 - mx), e1 = expf(wb1 - mx), e2 = expf(wb2 - mx);
    const float inv = 1.0f / (e0 + e1 + e2);
    const float b0 = e0 * inv, b1 = e1 * inv, b2 = e2 * inv;

    // lane n owns neighbor n's index and mixing weight (coalesced loads)
    const int nbr_own = seq_neighbor[bl * NN + chunk];
    const int rel_own = rel_neigh[bl * NN + chunk];
    const float w_own = rel_emb[rel_own * RR + 0] * b0
                      + rel_emb[rel_own * RR + 1] * b1
                      + rel_emb[rel_own * RR + 2] * b2;

    const float4* __restrict__ emb4 = (const float4*)user_emb;

    // start accumulator with the sequence row
    const int seq_idx = sequence[bl];
    float4 acc = emb4[(size_t)seq_idx * (DD / 4) + chunk];

    #pragma unroll 4
    for (int n = 0; n < NN; ++n) {
        const int   idx = __shfl(nbr_own, n, 32);   // broadcast within 32-lane group
        const float w   = __shfl(w_own,  n, 32);
        const float4 v  = emb4[(size_t)idx * (DD / 4) + chunk];
        acc.x += w * v.x;
        acc.y += w * v.y;
        acc.z += w * v.z;
        acc.w += w * v.w;
    }

    // L2 norm over the 128 dims = reduce acc·acc across the 32-lane group
    float ss = acc.x * acc.x + acc.y * acc.y + acc.z * acc.z + acc.w * acc.w;
    #pragma unroll
    for (int m = 16; m >= 1; m >>= 1)
        ss += __shfl_xor(ss, m, 32);

    const float rn = 1.0f / fmaxf(sqrtf(ss), 1e-12f);

    float4 o;
    o.x = acc.x * rn;
    o.y = acc.y * rn;
    o.z = acc.z * rn;
    o.w = acc.w * rn;
    ((float4*)out)[(size_t)bl * (DD / 4) + chunk] = o;
}

extern "C" void kernel_launch(void* const* d_in, const int* in_sizes, int n_in,
                              void* d_out, int out_size, void* d_ws, size_t ws_size,
                              hipStream_t stream) {
    const int*   sequence     = (const int*)d_in[0];
    const int*   seq_neighbor = (const int*)d_in[1];
    const int*   rel_neigh    = (const int*)d_in[2];
    const float* user_emb     = (const float*)d_in[3];
    const float* rel_emb      = (const float*)d_in[4];
    const float* weight_b     = (const float*)d_in[5];
    float*       out          = (float*)d_out;

    const int pairs = BB * LL;              // 12800
    const int grid  = pairs / 8;            // 1600 blocks of 256 threads (8 pairs each)
    subgl_kernel<<<grid, 256, 0, stream>>>(sequence, seq_neighbor, rel_neigh,
                                           user_emb, rel_emb, weight_b, out);
}